// Round 1
// baseline (507.314 us; speedup 1.0000x reference)
//
#include <hip/hip_runtime.h>
#include <stdint.h>

typedef __bf16  bf16x8  __attribute__((ext_vector_type(8)));
typedef float   f32x4   __attribute__((ext_vector_type(4)));
typedef unsigned short ushort8 __attribute__((ext_vector_type(8)));
typedef unsigned short ushort4v __attribute__((ext_vector_type(4)));

#define DEV __device__ __forceinline__

DEV unsigned short f2bf(float f) {
    union { float f; unsigned u; } v; v.f = f;
    unsigned u = v.u;
    unsigned r = (u + 0x7FFFu + ((u >> 16) & 1u)) >> 16;
    return (unsigned short)r;
}
DEV float bf2f(unsigned short h) {
    union { unsigned u; float f; } v; v.u = ((unsigned)h) << 16;
    return v.f;
}

DEV void gload16(const void* g, void* l) {
    __builtin_amdgcn_global_load_lds(
        (const __attribute__((address_space(1))) unsigned int*)g,
        (__attribute__((address_space(3))) unsigned int*)l, 16, 0, 0);
}

// ---------------------------------------------------------------------------
// Generic bf16 A*B^T GEMM, m97 structure: 128x128 tile, BK=32, 4 waves,
// global_load_lds width-16 staging, 16x16x32 bf16 MFMA.
// A: [M][K] row-major stride lda; B: [N][K] row-major stride ldb.
// C[m][n] = alpha * sum_k A[m][k]*B[n][k].  Batched via blockIdx.z.
// All of M, N multiples of 128; K multiple of 32.
// ---------------------------------------------------------------------------
template<bool OUT_BF16>
__global__ __launch_bounds__(256)
void gemm_bt(const unsigned short* __restrict__ A, long lda, long sA,
             const unsigned short* __restrict__ B, long ldb, long sB,
             void* __restrict__ Cv, long ldc, long sC,
             int M, int N, int K, float alpha)
{
    __shared__ unsigned short smA[128 * 32];
    __shared__ unsigned short smB[128 * 32];

    const int bz = blockIdx.z;
    A += (long)bz * sA;
    B += (long)bz * sB;

    const int tiles_n = N >> 7;
    const int tm = (int)blockIdx.x / tiles_n;
    const int tn = (int)blockIdx.x % tiles_n;
    const long brow = (long)tm * 128;
    const long bcol = (long)tn * 128;

    const int t    = threadIdx.x;
    const int wave = t >> 6;
    const int lane = t & 63;
    const int lr   = lane & 15;
    const int lk   = lane >> 4;
    const int wrow = (wave >> 1) * 64;
    const int wcol = (wave & 1) * 64;

    f32x4 acc[4][4];
#pragma unroll
    for (int m = 0; m < 4; ++m)
#pragma unroll
        for (int n = 0; n < 4; ++n)
            acc[m][n] = 0.f;

    // staging: 512 16B-loads per matrix tile; thread t covers i = t and i = 256+t
    // i -> row = i>>2, 16B segment = i&3 ; LDS byte offset = i*16 (row-major [128][32])
    const int r0 = t >> 2;
    const int s0 = t & 3;
    const unsigned short* gA = A + brow * lda + (long)s0 * 8;
    const unsigned short* gB = B + bcol * ldb + (long)s0 * 8;
    char* lA0 = (char*)smA + wave * 1024;          // wave-uniform LDS bases
    char* lA1 = (char*)smA + 4096 + wave * 1024;
    char* lB0 = (char*)smB + wave * 1024;
    char* lB1 = (char*)smB + 4096 + wave * 1024;

    const int nk = K >> 5;
    for (int kt = 0; kt < nk; ++kt) {
        const long kk = (long)kt * 32;
        __syncthreads();   // previous iteration's LDS reads complete
        gload16(gA + (long)r0 * lda + kk,        lA0);
        gload16(gA + (long)(r0 + 64) * lda + kk, lA1);
        gload16(gB + (long)r0 * ldb + kk,        lB0);
        gload16(gB + (long)(r0 + 64) * ldb + kk, lB1);
        asm volatile("s_waitcnt vmcnt(0)" ::: "memory");
        __syncthreads();   // staged data visible

        bf16x8 af[4], bfr[4];
#pragma unroll
        for (int m = 0; m < 4; ++m)
            af[m] = *(const bf16x8*)(smA + ((wrow + m * 16 + lr) * 32 + lk * 8));
#pragma unroll
        for (int n = 0; n < 4; ++n)
            bfr[n] = *(const bf16x8*)(smB + ((wcol + n * 16 + lr) * 32 + lk * 8));
#pragma unroll
        for (int m = 0; m < 4; ++m)
#pragma unroll
            for (int n = 0; n < 4; ++n)
                acc[m][n] = __builtin_amdgcn_mfma_f32_16x16x32_bf16(
                    af[m], bfr[n], acc[m][n], 0, 0, 0);
    }

    // epilogue: D layout col = lane&15, row = (lane>>4)*4 + j   [m89]
    if (OUT_BF16) {
        unsigned short* C = (unsigned short*)Cv + (long)bz * sC;
#pragma unroll
        for (int m = 0; m < 4; ++m)
#pragma unroll
            for (int n = 0; n < 4; ++n) {
                const long c = bcol + wcol + n * 16 + lr;
#pragma unroll
                for (int j = 0; j < 4; ++j) {
                    const long r = brow + wrow + m * 16 + lk * 4 + j;
                    C[r * ldc + c] = f2bf(acc[m][n][j] * alpha);
                }
            }
    } else {
        float* C = (float*)Cv + (long)bz * sC;
#pragma unroll
        for (int m = 0; m < 4; ++m)
#pragma unroll
            for (int n = 0; n < 4; ++n) {
                const long c = bcol + wcol + n * 16 + lr;
#pragma unroll
                for (int j = 0; j < 4; ++j) {
                    const long r = brow + wrow + m * 16 + lk * 4 + j;
                    C[r * ldc + c] = acc[m][n][j] * alpha;
                }
            }
    }
}

// ---------------------------------------------------------------------------
// fp32 -> bf16 elementwise (vectorized), grid-stride
// ---------------------------------------------------------------------------
__global__ __launch_bounds__(256)
void conv_x(const f32x4* __restrict__ X, ushort4v* __restrict__ Y, long n4)
{
    long i = (long)blockIdx.x * 256 + threadIdx.x;
    const long stride = (long)gridDim.x * 256;
    for (; i < n4; i += stride) {
        f32x4 v = X[i];
        ushort4v o;
#pragma unroll
        for (int j = 0; j < 4; ++j) o[j] = f2bf(v[j]);
        Y[i] = o;
    }
}

// ---------------------------------------------------------------------------
// W [3][1024][1024] fp32  ->  Wt [3][1024][1024] bf16, transposed per head:
// Wt[h][o][d] = W[h][d][o].  64x64 LDS tile transpose.
// ---------------------------------------------------------------------------
__global__ __launch_bounds__(256)
void conv_w(const float* __restrict__ W, unsigned short* __restrict__ Wt)
{
    __shared__ unsigned short tile[64][65];
    const long hofs = (long)blockIdx.z * 1048576;
    const int d0 = blockIdx.x * 64;
    const int o0 = blockIdx.y * 64;
    const int t = threadIdx.x;
    const int c  = t & 63;
    const int r0 = t >> 6;
#pragma unroll
    for (int rr = 0; rr < 64; rr += 4) {
        const int r = rr + r0;
        tile[r][c] = f2bf(W[hofs + (long)(d0 + r) * 1024 + (o0 + c)]);
    }
    __syncthreads();
#pragma unroll
    for (int rr = 0; rr < 64; rr += 4) {
        const int r = rr + r0;
        Wt[hofs + (long)(o0 + r) * 1024 + (d0 + c)] = tile[c][r];
    }
}

// ---------------------------------------------------------------------------
// row softmax in place on bf16 [nrows][2048]; one block per row.
// 256 threads * 8 elements, fp32 math.
// ---------------------------------------------------------------------------
__global__ __launch_bounds__(256)
void softmax_rows(unsigned short* __restrict__ P)
{
    __shared__ float red[4];
    unsigned short* p = P + (long)blockIdx.x * 2048;
    const int t = threadIdx.x;
    const int lane = t & 63, wave = t >> 6;

    ushort8 u = *(const ushort8*)(p + t * 8);
    float x[8];
    float mx = -3.0e38f;
#pragma unroll
    for (int j = 0; j < 8; ++j) { x[j] = bf2f(u[j]); mx = fmaxf(mx, x[j]); }
#pragma unroll
    for (int o = 1; o < 64; o <<= 1) mx = fmaxf(mx, __shfl_xor(mx, o));
    if (lane == 0) red[wave] = mx;
    __syncthreads();
    mx = fmaxf(fmaxf(red[0], red[1]), fmaxf(red[2], red[3]));
    __syncthreads();

    float e[8], s = 0.f;
#pragma unroll
    for (int j = 0; j < 8; ++j) { e[j] = __expf(x[j] - mx); s += e[j]; }
#pragma unroll
    for (int o = 1; o < 64; o <<= 1) s += __shfl_xor(s, o);
    if (lane == 0) red[wave] = s;
    __syncthreads();
    s = red[0] + red[1] + red[2] + red[3];

    const float inv = 1.0f / s;
    ushort8 o8;
#pragma unroll
    for (int j = 0; j < 8; ++j) o8[j] = f2bf(e[j] * inv);
    *(ushort8*)(p + t * 8) = o8;
}

// ---------------------------------------------------------------------------
extern "C" void kernel_launch(void* const* d_in, const int* in_sizes, int n_in,
                              void* d_out, int out_size, void* d_ws, size_t ws_size,
                              hipStream_t stream)
{
    const float* x = (const float*)d_in[0];   // [8,2048,1024]
    const float* w = (const float*)d_in[1];   // [3,1024,1024]
    float* out = (float*)d_out;               // [8,2048,1024] fp32

    const long BS = 16384;   // 8*2048 flattened rows
    const long D  = 1024;
    const long S  = 2048;

    char* ws = (char*)d_ws;
    unsigned short* Xb = (unsigned short*)ws; ws += BS * D * 2;            // 32 MB
    unsigned short* Wt = (unsigned short*)ws; ws += 3L * D * D * 2;        // 6 MB
    unsigned short* QK = (unsigned short*)ws; ws += BS * 2 * D * 2;        // 64 MB
    unsigned short* Vt = (unsigned short*)ws; ws += D * BS * 2;            // 32 MB
    unsigned short* P  = (unsigned short*)ws; ws += 8L * S * S * 2;        // 64 MB

    // 1) x -> bf16
    conv_x<<<4096, 256, 0, stream>>>((const f32x4*)x, (ushort4v*)Xb, BS * D / 4);
    // 2) W -> bf16, transposed per head
    conv_w<<<dim3(16, 16, 3), 256, 0, stream>>>(w, Wt);

    // 3) QK = Xb * [W0|W1]^T  -> [16384][2048] bf16 (cols 0..1023 = Q, 1024..2047 = K)
    gemm_bt<true><<<dim3((BS / 128) * (2048 / 128), 1, 1), 256, 0, stream>>>(
        Xb, D, 0, Wt, D, 0, QK, 2 * D, 0, (int)BS, 2048, (int)D, 1.f);

    // 4) Vt[o][bs] = sum_d W2t[o][d] * Xb[bs][d]   -> [1024][16384] bf16
    gemm_bt<true><<<dim3((1024 / 128) * (BS / 128), 1, 1), 256, 0, stream>>>(
        Wt + 2L * D * D, D, 0, Xb, D, 0, Vt, BS, 0, 1024, (int)BS, (int)D, 1.f);

    // 5) scores_b = Q_b * K_b^T / sqrt(2048)  -> P bf16   (batched z=8)
    gemm_bt<true><<<dim3((S / 128) * (S / 128), 1, 8), 256, 0, stream>>>(
        QK, 2 * D, S * 2 * D,            // A = Q_b
        QK + D, 2 * D, S * 2 * D,        // B = K_b
        P, S, S * S,                     // C = P_b
        (int)S, (int)S, (int)D, 0.022097086912079612f);

    // 6) softmax rows in place
    softmax_rows<<<16384, 256, 0, stream>>>(P);

    // 7) out_b = P_b * Vt_b^T  (fp32 out)   (batched z=8)
    gemm_bt<false><<<dim3((S / 128) * (1024 / 128), 1, 8), 256, 0, stream>>>(
        P, S, S * S,                     // A = P_b
        Vt, BS, S,                       // B = Vt columns for batch b
        out, D, S * D,                   // C = out_b
        (int)S, 1024, (int)S, 1.f);
}

// Round 2
// 388.871 us; speedup vs baseline: 1.3046x; 1.3046x over previous
//
#include <hip/hip_runtime.h>
#include <stdint.h>

typedef __bf16  bf16x8  __attribute__((ext_vector_type(8)));
typedef float   f32x4   __attribute__((ext_vector_type(4)));
typedef unsigned short ushort8 __attribute__((ext_vector_type(8)));
typedef unsigned short ushort4v __attribute__((ext_vector_type(4)));

#define DEV __device__ __forceinline__

DEV unsigned short f2bf(float f) {
    union { float f; unsigned u; } v; v.f = f;
    unsigned u = v.u;
    return (unsigned short)((u + 0x7FFFu + ((u >> 16) & 1u)) >> 16);
}
DEV float bf2f(unsigned short h) {
    union { unsigned u; float f; } v; v.u = ((unsigned)h) << 16;
    return v.f;
}

DEV void gload16(const void* g, void* l) {
    __builtin_amdgcn_global_load_lds(
        (const __attribute__((address_space(1))) unsigned int*)g,
        (__attribute__((address_space(3))) unsigned int*)l, 16, 0, 0);
}

// ===========================================================================
// 256x256 tile, BK=64, 8 waves (2Mx4N), double-buffered LDS (128 KiB),
// counted-vmcnt deep pipeline, XOR-swizzled LDS, A[M][K] * B[N][K]^T.
// Schedule (per K-tile, 4 phases):
//   P1: ds_read Aq0+Bn01 | stage B0(t+1)->buf^1 | bar | MFMA q0n01 | bar
//   P2: ds_read Aq1+Bn23 | stage B1(t+1)->buf^1 | bar | MFMA q0n23 | lgkmcnt(0) | bar
//   P3: stage A0(t+2)->buf (A-reads all drained) | MFMA q1n01 | bar
//   P4: stage A1(t+2)->buf | vmcnt(4) | MFMA q1n23 | bar
// Steady state: 2 half-tiles (4 loads/lane) in flight across each boundary.
// ===========================================================================
template<bool OUT_BF16>
__global__ __launch_bounds__(512, 2)
void gemm256(const unsigned short* __restrict__ A, long lda, long sA,
             const unsigned short* __restrict__ B, long ldb, long sB,
             void* __restrict__ Cv, long ldc, long sC,
             int N, int K, float alpha)
{
    __shared__ __attribute__((aligned(16))) char sm[131072];

    const int bz = blockIdx.z;
    A += (long)bz * sA;
    B += (long)bz * sB;

    const int tiles_n = N >> 8;
    int bid = blockIdx.x;
    const int nwg = gridDim.x;
    {   // bijective XCD swizzle (m204)
        const int q = nwg >> 3, r = nwg & 7;
        const int xcd = bid & 7, idx = bid >> 3;
        bid = (xcd < r ? xcd * (q + 1) : r * (q + 1) + (xcd - r) * q) + idx;
    }
    const long brow = (long)(bid / tiles_n) << 8;
    const long bcol = (long)(bid % tiles_n) << 8;

    const int t = threadIdx.x;
    const int w = t >> 6, lane = t & 63;
    const int wr = w >> 2, wc = w & 3;
    const int lr = lane & 15, lk = lane >> 4;

    // ---- staging geometry (pre-swizzled global source, linear LDS dest) ----
    const int srow = (w << 3) + (lane >> 3);                 // 0..63
    const int scol = ((lane & 7) ^ (lane >> 3)) << 3;        // swizzled col (elems)
    const unsigned short* gA = A + (brow + srow) * lda + scol;
    const unsigned short* gB = B + (bcol + srow) * ldb + scol;
    char* const dstA = sm + w * 1024;                        // +buf*65536 +half*16384 (+8192)
    char* const dstB = sm + 32768 + w * 1024;

    // ---- reader geometry (XOR swizzle on colbyte: ^ (row&7)<<4) ----
    const int rsw0 = ((lk ^ (lr & 7)) << 4);                 // ks=0 colbyte; ks=1 -> ^64
    const int aoff = wr * 16384 + lr * 128;
    const int boff = 32768 + (wc >> 1) * 16384 + (((wc & 1) << 6) + lr) * 128;

    f32x4 acc[8][4];
#pragma unroll
    for (int m = 0; m < 8; ++m)
#pragma unroll
        for (int n = 0; n < 4; ++n) acc[m][n] = 0.f;

    const int nk = K >> 6;

#define STAGE_A(buf, half, kt) { \
    const unsigned short* s_ = gA + (long)((half) * 128) * lda + (long)(kt) * 64; \
    char* d_ = dstA + (buf) * 65536 + (half) * 16384; \
    gload16(s_, d_); gload16(s_ + 64 * lda, d_ + 8192); }
#define STAGE_B(buf, half, kt) { \
    const unsigned short* s_ = gB + (long)((half) * 128) * ldb + (long)(kt) * 64; \
    char* d_ = dstB + (buf) * 65536 + (half) * 16384; \
    gload16(s_, d_); gload16(s_ + 64 * ldb, d_ + 8192); }

    // ---- prologue: tile0 (4 halves) + A-halves of tile1 ----
    STAGE_A(0, 0, 0); STAGE_A(0, 1, 0); STAGE_B(0, 0, 0); STAGE_B(0, 1, 0);
    if (nk > 1) {
        STAGE_A(1, 0, 1); STAGE_A(1, 1, 1);
        asm volatile("s_waitcnt vmcnt(4)" ::: "memory");
    } else {
        asm volatile("s_waitcnt vmcnt(0)" ::: "memory");
    }
    __builtin_amdgcn_s_barrier();

    for (int kt = 0; kt < nk; ++kt) {
        const int buf = kt & 1;
        const char* sa = sm + buf * 65536 + aoff;
        const char* sb = sm + buf * 65536 + boff;
        bf16x8 a[8][2], b[4][2];

        // ---------------- P1 ----------------
#pragma unroll
        for (int m = 0; m < 4; ++m) {
            a[m][0] = *(const bf16x8*)(sa + m * 2048 + rsw0);
            a[m][1] = *(const bf16x8*)(sa + m * 2048 + (rsw0 ^ 64));
        }
#pragma unroll
        for (int n = 0; n < 2; ++n) {
            b[n][0] = *(const bf16x8*)(sb + n * 2048 + rsw0);
            b[n][1] = *(const bf16x8*)(sb + n * 2048 + (rsw0 ^ 64));
        }
        if (kt + 1 < nk) STAGE_B(buf ^ 1, 0, kt + 1);
        __builtin_amdgcn_s_barrier();
        __builtin_amdgcn_s_setprio(1);
#pragma unroll
        for (int m = 0; m < 4; ++m)
#pragma unroll
            for (int n = 0; n < 2; ++n)
#pragma unroll
                for (int ks = 0; ks < 2; ++ks)
                    acc[m][n] = __builtin_amdgcn_mfma_f32_16x16x32_bf16(
                        a[m][ks], b[n][ks], acc[m][n], 0, 0, 0);
        __builtin_amdgcn_s_setprio(0);
        __builtin_amdgcn_s_barrier();

        // ---------------- P2 ----------------
#pragma unroll
        for (int m = 4; m < 8; ++m) {
            a[m][0] = *(const bf16x8*)(sa + m * 2048 + rsw0);
            a[m][1] = *(const bf16x8*)(sa + m * 2048 + (rsw0 ^ 64));
        }
#pragma unroll
        for (int n = 2; n < 4; ++n) {
            b[n][0] = *(const bf16x8*)(sb + n * 2048 + rsw0);
            b[n][1] = *(const bf16x8*)(sb + n * 2048 + (rsw0 ^ 64));
        }
        if (kt + 1 < nk) STAGE_B(buf ^ 1, 1, kt + 1);
        __builtin_amdgcn_s_barrier();
        __builtin_amdgcn_s_setprio(1);
#pragma unroll
        for (int m = 0; m < 4; ++m)
#pragma unroll
            for (int n = 2; n < 4; ++n)
#pragma unroll
                for (int ks = 0; ks < 2; ++ks)
                    acc[m][n] = __builtin_amdgcn_mfma_f32_16x16x32_bf16(
                        a[m][ks], b[n][ks], acc[m][n], 0, 0, 0);
        __builtin_amdgcn_s_setprio(0);
        // all reads of this buffer (incl. a[4..7], b[2..3]) must be serviced
        // before any wave overwrites this buffer's A-regions in P3/P4:
        asm volatile("s_waitcnt lgkmcnt(0)" ::: "memory");
        __builtin_amdgcn_s_barrier();

        // ---------------- P3 ----------------
        if (kt + 2 < nk) STAGE_A(buf, 0, kt + 2);
        __builtin_amdgcn_s_setprio(1);
#pragma unroll
        for (int m = 4; m < 8; ++m)
#pragma unroll
            for (int n = 0; n < 2; ++n)
#pragma unroll
                for (int ks = 0; ks < 2; ++ks)
                    acc[m][n] = __builtin_amdgcn_mfma_f32_16x16x32_bf16(
                        a[m][ks], b[n][ks], acc[m][n], 0, 0, 0);
        __builtin_amdgcn_s_setprio(0);
        __builtin_amdgcn_s_barrier();

        // ---------------- P4 ----------------
        if (kt + 2 < nk) {
            STAGE_A(buf, 1, kt + 2);
            asm volatile("s_waitcnt vmcnt(4)" ::: "memory");
        } else if (kt + 1 < nk) {
            asm volatile("s_waitcnt vmcnt(0)" ::: "memory");
        }
        __builtin_amdgcn_s_setprio(1);
#pragma unroll
        for (int m = 4; m < 8; ++m)
#pragma unroll
            for (int n = 2; n < 4; ++n)
#pragma unroll
                for (int ks = 0; ks < 2; ++ks)
                    acc[m][n] = __builtin_amdgcn_mfma_f32_16x16x32_bf16(
                        a[m][ks], b[n][ks], acc[m][n], 0, 0, 0);
        __builtin_amdgcn_s_setprio(0);
        __builtin_amdgcn_s_barrier();
    }
#undef STAGE_A
#undef STAGE_B

    // ---- epilogue: C/D layout col = lane&15, row = (lane>>4)*4 + j ----
    const long r0 = brow + wr * 128;
    const long c0 = bcol + wc * 64;
    if (OUT_BF16) {
        unsigned short* C = (unsigned short*)Cv + (long)bz * sC;
#pragma unroll
        for (int m = 0; m < 8; ++m)
#pragma unroll
            for (int n = 0; n < 4; ++n) {
                const long c = c0 + n * 16 + lr;
#pragma unroll
                for (int j = 0; j < 4; ++j) {
                    const long r = r0 + m * 16 + lk * 4 + j;
                    C[r * ldc + c] = f2bf(acc[m][n][j] * alpha);
                }
            }
    } else {
        float* C = (float*)Cv + (long)bz * sC;
#pragma unroll
        for (int m = 0; m < 8; ++m)
#pragma unroll
            for (int n = 0; n < 4; ++n) {
                const long c = c0 + n * 16 + lr;
#pragma unroll
                for (int j = 0; j < 4; ++j) {
                    const long r = r0 + m * 16 + lk * 4 + j;
                    C[r * ldc + c] = acc[m][n][j] * alpha;
                }
            }
    }
}

// ---------------------------------------------------------------------------
// fp32 -> bf16 elementwise (vectorized), grid-stride
// ---------------------------------------------------------------------------
__global__ __launch_bounds__(256)
void conv_x(const f32x4* __restrict__ X, ushort4v* __restrict__ Y, long n4)
{
    long i = (long)blockIdx.x * 256 + threadIdx.x;
    const long stride = (long)gridDim.x * 256;
    for (; i < n4; i += stride) {
        f32x4 v = X[i];
        ushort4v o;
#pragma unroll
        for (int j = 0; j < 4; ++j) o[j] = f2bf(v[j]);
        Y[i] = o;
    }
}

// ---------------------------------------------------------------------------
// W [3][1024][1024] fp32 -> Wt [3][1024][1024] bf16 transposed per head
// ---------------------------------------------------------------------------
__global__ __launch_bounds__(256)
void conv_w(const float* __restrict__ W, unsigned short* __restrict__ Wt)
{
    __shared__ unsigned short tile[64][65];
    const long hofs = (long)blockIdx.z * 1048576;
    const int d0 = blockIdx.x * 64;
    const int o0 = blockIdx.y * 64;
    const int t = threadIdx.x;
    const int c  = t & 63;
    const int r0 = t >> 6;
#pragma unroll
    for (int rr = 0; rr < 64; rr += 4) {
        const int r = rr + r0;
        tile[r][c] = f2bf(W[hofs + (long)(d0 + r) * 1024 + (o0 + c)]);
    }
    __syncthreads();
#pragma unroll
    for (int rr = 0; rr < 64; rr += 4) {
        const int r = rr + r0;
        Wt[hofs + (long)(o0 + r) * 1024 + (d0 + c)] = tile[c][r];
    }
}

// ---------------------------------------------------------------------------
// row softmax in place on bf16 [nrows][2048]; one block per row
// ---------------------------------------------------------------------------
__global__ __launch_bounds__(256)
void softmax_rows(unsigned short* __restrict__ P)
{
    __shared__ float red[4];
    unsigned short* p = P + (long)blockIdx.x * 2048;
    const int t = threadIdx.x;
    const int lane = t & 63, wave = t >> 6;

    ushort8 u = *(const ushort8*)(p + t * 8);
    float x[8];
    float mx = -3.0e38f;
#pragma unroll
    for (int j = 0; j < 8; ++j) { x[j] = bf2f(u[j]); mx = fmaxf(mx, x[j]); }
#pragma unroll
    for (int o = 1; o < 64; o <<= 1) mx = fmaxf(mx, __shfl_xor(mx, o));
    if (lane == 0) red[wave] = mx;
    __syncthreads();
    mx = fmaxf(fmaxf(red[0], red[1]), fmaxf(red[2], red[3]));
    __syncthreads();

    float e[8], s = 0.f;
#pragma unroll
    for (int j = 0; j < 8; ++j) { e[j] = __expf(x[j] - mx); s += e[j]; }
#pragma unroll
    for (int o = 1; o < 64; o <<= 1) s += __shfl_xor(s, o);
    if (lane == 0) red[wave] = s;
    __syncthreads();
    s = red[0] + red[1] + red[2] + red[3];

    const float inv = 1.0f / s;
    ushort8 o8;
#pragma unroll
    for (int j = 0; j < 8; ++j) o8[j] = f2bf(e[j] * inv);
    *(ushort8*)(p + t * 8) = o8;
}

// ---------------------------------------------------------------------------
extern "C" void kernel_launch(void* const* d_in, const int* in_sizes, int n_in,
                              void* d_out, int out_size, void* d_ws, size_t ws_size,
                              hipStream_t stream)
{
    const float* x = (const float*)d_in[0];   // [8,2048,1024]
    const float* w = (const float*)d_in[1];   // [3,1024,1024]
    float* out = (float*)d_out;               // [8,2048,1024] fp32

    const long BS = 16384;   // 8*2048 flattened rows
    const long D  = 1024;
    const long S  = 2048;

    char* ws = (char*)d_ws;
    unsigned short* Xb = (unsigned short*)ws; ws += BS * D * 2;            // 32 MB
    unsigned short* Wt = (unsigned short*)ws; ws += 3L * D * D * 2;        // 6 MB
    unsigned short* QK = (unsigned short*)ws; ws += BS * 2 * D * 2;        // 64 MB
    unsigned short* Vt = (unsigned short*)ws; ws += D * BS * 2;            // 32 MB
    unsigned short* P  = (unsigned short*)ws; ws += 8L * S * S * 2;        // 64 MB

    // 1) x -> bf16
    conv_x<<<4096, 256, 0, stream>>>((const f32x4*)x, (ushort4v*)Xb, BS * D / 4);
    // 2) W -> bf16, transposed per head
    conv_w<<<dim3(16, 16, 3), 256, 0, stream>>>(w, Wt);

    // 3) QK = Xb * [W0|W1]^T -> [16384][2048] bf16 (cols 0..1023=Q, 1024..2047=K)
    gemm256<true><<<dim3((BS / 256) * (2048 / 256), 1, 1), 512, 0, stream>>>(
        Xb, D, 0, Wt, D, 0, QK, 2 * D, 0, 2048, (int)D, 1.f);

    // 4) Vt[o][bs] = sum_d W2t[o][d] * Xb[bs][d] -> [1024][16384] bf16
    gemm256<true><<<dim3((1024 / 256) * (BS / 256), 1, 1), 512, 0, stream>>>(
        Wt + 2L * D * D, D, 0, Xb, D, 0, Vt, BS, 0, (int)BS, (int)D, 1.f);

    // 5) scores_b = Q_b * K_b^T / sqrt(2048) -> P bf16   (batched z=8)
    gemm256<true><<<dim3((S / 256) * (S / 256), 1, 8), 512, 0, stream>>>(
        QK, 2 * D, S * 2 * D,
        QK + D, 2 * D, S * 2 * D,
        P, S, S * S,
        (int)S, (int)D, 0.022097086912079612f);

    // 6) softmax rows in place
    softmax_rows<<<16384, 256, 0, stream>>>(P);

    // 7) out_b = P_b * Vt_b^T (fp32 out)   (batched z=8)
    gemm256<false><<<dim3((S / 256) * (1024 / 256), 1, 8), 512, 0, stream>>>(
        P, S, S * S,
        Vt, BS, S,
        out, D, S * D,
        1024, (int)S, 1.f);
}